// Round 1
// baseline (270.497 us; speedup 1.0000x reference)
//
#include <hip/hip_runtime.h>
#include <hip/hip_bf16.h>
#include <stdint.h>

typedef __bf16 bf16;
typedef __attribute__((ext_vector_type(8))) __bf16 bf16x8;
typedef __attribute__((ext_vector_type(4))) float f32x4;

#define BZ 4
#define NN 2048
#define CC 1024

// ---------------- fp32 -> bf16 flat convert (8 elems/thread) ----------------
__global__ void cvt_f32_bf16(const float* __restrict__ in, bf16* __restrict__ out, int n8) {
    int i = blockIdx.x * blockDim.x + threadIdx.x;
    if (i >= n8) return;
    const float4* p = (const float4*)in;
    float4 a = p[2 * i], b = p[2 * i + 1];
    bf16x8 o;
    o[0] = (bf16)a.x; o[1] = (bf16)a.y; o[2] = (bf16)a.z; o[3] = (bf16)a.w;
    o[4] = (bf16)b.x; o[5] = (bf16)b.y; o[6] = (bf16)b.z; o[7] = (bf16)b.w;
    *(bf16x8*)(out + 8 * (size_t)i) = o;
}

// ---------------- W [C][C] f32 -> Wt [C][C] bf16 transposed ----------------
__global__ void transposeW(const float* __restrict__ W, bf16* __restrict__ Wt) {
    __shared__ bf16 t[32][33];
    int d0 = blockIdx.x * 32, c0 = blockIdx.y * 32;
    int tx = threadIdx.x, ty = threadIdx.y;  // 32x8
#pragma unroll
    for (int i = 0; i < 4; i++)
        t[ty + 8 * i][tx] = (bf16)W[(size_t)(c0 + ty + 8 * i) * CC + d0 + tx];
    __syncthreads();
#pragma unroll
    for (int i = 0; i < 4; i++)
        Wt[(size_t)(d0 + ty + 8 * i) * CC + c0 + tx] = t[tx][ty + 8 * i];
}

// ---------------- v [B*N][C] bf16 -> vT [B][C][N] bf16 ----------------
__global__ void transposeV(const bf16* __restrict__ V, bf16* __restrict__ VT) {
    __shared__ bf16 t[32][33];
    int b = blockIdx.z;
    int n0 = blockIdx.x * 32, c0 = blockIdx.y * 32;
    const bf16* Vb = V + (size_t)b * NN * CC;
    bf16* Tb = VT + (size_t)b * CC * NN;
    int tx = threadIdx.x, ty = threadIdx.y;  // 32x8
#pragma unroll
    for (int i = 0; i < 4; i++)
        t[ty + 8 * i][tx] = Vb[(size_t)(n0 + ty + 8 * i) * CC + c0 + tx];
    __syncthreads();
#pragma unroll
    for (int i = 0; i < 4; i++)
        Tb[(size_t)(c0 + ty + 8 * i) * NN + n0 + tx] = t[tx][ty + 8 * i];
}

// ---------------- bf16 B^T GEMM: C[m][n] = scale * sum_k A[m][k]*Bt[n][k] + bias[n] ----
// lda == ldb == K, ldc == Nd for all our calls.
template <bool OUT_F32>
__global__ __launch_bounds__(256) void gemm_bt(
    const bf16* __restrict__ A, const bf16* __restrict__ Bt,
    void* __restrict__ Cout, const float* __restrict__ bias,
    int M, int Nd, int K, float scale,
    long long sA, long long sB, long long sC) {
    constexpr int BM = 128, BN = 128, BK = 32, SK = 40;  // SK: +8 pad, conflict-free
    __shared__ __align__(16) bf16 As[BM * SK];
    __shared__ __align__(16) bf16 Bs[BN * SK];
    const int b = blockIdx.z;
    A += (size_t)b * sA;
    Bt += (size_t)b * sB;
    const int m0 = blockIdx.y * BM, n0 = blockIdx.x * BN;
    const int t = threadIdx.x;
    const int wave = t >> 6, lane = t & 63;
    const int wm = (wave >> 1) * 64, wn = (wave & 1) * 64;  // 2x2 waves of 64x64
    f32x4 acc[4][4] = {};

    const int sr = t >> 2;        // staging row 0..63
    const int sc = (t & 3) * 8;   // staging col chunk (8 bf16 = 16B)
    const int fr = lane & 15, hk = (lane >> 4) * 8;

    for (int k0 = 0; k0 < K; k0 += BK) {
        uint4 a0 = *(const uint4*)(A + (size_t)(m0 + sr) * K + k0 + sc);
        uint4 a1 = *(const uint4*)(A + (size_t)(m0 + sr + 64) * K + k0 + sc);
        uint4 b0 = *(const uint4*)(Bt + (size_t)(n0 + sr) * K + k0 + sc);
        uint4 b1 = *(const uint4*)(Bt + (size_t)(n0 + sr + 64) * K + k0 + sc);
        __syncthreads();  // previous iter's compute done before overwrite
        *(uint4*)&As[sr * SK + sc] = a0;
        *(uint4*)&As[(sr + 64) * SK + sc] = a1;
        *(uint4*)&Bs[sr * SK + sc] = b0;
        *(uint4*)&Bs[(sr + 64) * SK + sc] = b1;
        __syncthreads();
        bf16x8 af[4], bfr[4];
#pragma unroll
        for (int i = 0; i < 4; i++)
            af[i] = *(const bf16x8*)&As[(wm + i * 16 + fr) * SK + hk];
#pragma unroll
        for (int j = 0; j < 4; j++)
            bfr[j] = *(const bf16x8*)&Bs[(wn + j * 16 + fr) * SK + hk];
#pragma unroll
        for (int i = 0; i < 4; i++)
#pragma unroll
            for (int j = 0; j < 4; j++)
                acc[i][j] = __builtin_amdgcn_mfma_f32_16x16x32_bf16(af[i], bfr[j], acc[i][j], 0, 0, 0);
    }

    const int rq = (lane >> 4) * 4;
#pragma unroll
    for (int i = 0; i < 4; i++) {
#pragma unroll
        for (int j = 0; j < 4; j++) {
            int col = n0 + wn + j * 16 + fr;
            float bb = bias ? bias[col] : 0.f;
#pragma unroll
            for (int r = 0; r < 4; r++) {
                int row = m0 + wm + i * 16 + rq + r;
                float v = acc[i][j][r] * scale + bb;
                if (OUT_F32)
                    ((float*)Cout)[(size_t)b * sC + (size_t)row * Nd + col] = v;
                else
                    ((bf16*)Cout)[(size_t)b * sC + (size_t)row * Nd + col] = (bf16)v;
            }
        }
    }
}

// ---------------- row softmax in place, rows of 2048 bf16 ----------------
__global__ __launch_bounds__(256) void softmax_rows(bf16* __restrict__ S) {
    const size_t row = blockIdx.x;
    bf16* p = S + row * (size_t)NN;
    const int t = threadIdx.x;
    bf16x8 vv = *(const bf16x8*)(p + t * 8);
    float f[8];
    float m = -1e30f;
#pragma unroll
    for (int i = 0; i < 8; i++) { f[i] = (float)vv[i]; m = fmaxf(m, f[i]); }
#pragma unroll
    for (int off = 32; off; off >>= 1) m = fmaxf(m, __shfl_xor(m, off));
    __shared__ float redm[4], reds[4];
    int wave = t >> 6, lane = t & 63;
    if (lane == 0) redm[wave] = m;
    __syncthreads();
    m = fmaxf(fmaxf(redm[0], redm[1]), fmaxf(redm[2], redm[3]));
    float s = 0.f;
#pragma unroll
    for (int i = 0; i < 8; i++) { f[i] = __expf(f[i] - m); s += f[i]; }
#pragma unroll
    for (int off = 32; off; off >>= 1) s += __shfl_xor(s, off);
    if (lane == 0) reds[wave] = s;
    __syncthreads();
    s = reds[0] + reds[1] + reds[2] + reds[3];
    float inv = 1.f / s;
    bf16x8 ov;
#pragma unroll
    for (int i = 0; i < 8; i++) ov[i] = (bf16)(f[i] * inv);
    *(bf16x8*)(p + t * 8) = ov;
}

extern "C" void kernel_launch(void* const* d_in, const int* in_sizes, int n_in,
                              void* d_out, int out_size, void* d_ws, size_t ws_size,
                              hipStream_t stream) {
    const float* event_f = (const float*)d_in[0];
    const float* img_f   = (const float*)d_in[1];
    const float* Wq = (const float*)d_in[2];
    const float* bq = (const float*)d_in[3];
    const float* Wk = (const float*)d_in[4];
    const float* bk = (const float*)d_in[5];
    const float* Wv = (const float*)d_in[6];
    const float* bv = (const float*)d_in[7];
    float* out = (float*)d_out;

    bf16* ws = (bf16*)d_ws;
    size_t off = 0;
    const size_t MC = (size_t)BZ * NN * CC;  // 8388608
    bf16* Ebf = ws + off; off += MC;
    bf16* Ibf = ws + off; off += MC;
    bf16* Wqt = ws + off; off += (size_t)CC * CC;
    bf16* Wkt = ws + off; off += (size_t)CC * CC;
    bf16* Wvt = ws + off; off += (size_t)CC * CC;
    bf16* Q   = ws + off; off += MC;
    bf16* K_  = ws + off; off += MC;
    bf16* V_  = ws + off; off += MC;
    bf16* VT  = ws + off; off += MC;
    bf16* S   = ws + off; off += (size_t)BZ * NN * NN;  // 16777216

    // 1. convert inputs to bf16
    {
        int n8 = (int)(MC / 8);
        cvt_f32_bf16<<<dim3((n8 + 255) / 256), dim3(256), 0, stream>>>(event_f, Ebf, n8);
        cvt_f32_bf16<<<dim3((n8 + 255) / 256), dim3(256), 0, stream>>>(img_f, Ibf, n8);
    }
    // 2. transpose weights to bf16 [d][c]
    {
        dim3 g(CC / 32, CC / 32), b(32, 8);
        transposeW<<<g, b, 0, stream>>>(Wq, Wqt);
        transposeW<<<g, b, 0, stream>>>(Wk, Wkt);
        transposeW<<<g, b, 0, stream>>>(Wv, Wvt);
    }
    // 3. projections: q/k/v = X @ W + b  (M=8192, N=1024, K=1024)
    {
        dim3 g(CC / 128, (BZ * NN) / 128, 1), b(256);
        gemm_bt<false><<<g, b, 0, stream>>>(Ebf, Wqt, Q,  bq, BZ * NN, CC, CC, 1.f, 0, 0, 0);
        gemm_bt<false><<<g, b, 0, stream>>>(Ibf, Wkt, K_, bk, BZ * NN, CC, CC, 1.f, 0, 0, 0);
        gemm_bt<false><<<g, b, 0, stream>>>(Ibf, Wvt, V_, bv, BZ * NN, CC, CC, 1.f, 0, 0, 0);
    }
    // 4. transpose V per batch -> [B][C][N]
    {
        dim3 g(NN / 32, CC / 32, BZ), b(32, 8);
        transposeV<<<g, b, 0, stream>>>(V_, VT);
    }
    // 5. S = Q @ K^T * (1/32)   (per batch: 2048x2048, K=1024)
    {
        dim3 g(NN / 128, NN / 128, BZ), b(256);
        gemm_bt<false><<<g, b, 0, stream>>>(Q, K_, S, nullptr, NN, NN, CC,
                                            1.f / 32.f,
                                            (long long)NN * CC, (long long)NN * CC,
                                            (long long)NN * NN);
    }
    // 6. softmax rows in place
    softmax_rows<<<dim3(BZ * NN), dim3(256), 0, stream>>>(S);
    // 7. out = P @ V  (per batch: 2048x1024, K=2048) -> fp32 d_out
    {
        dim3 g(CC / 128, NN / 128, BZ), b(256);
        gemm_bt<true><<<g, b, 0, stream>>>(S, VT, out, nullptr, NN, CC, NN, 1.f,
                                           (long long)NN * NN, (long long)CC * NN,
                                           (long long)NN * CC);
    }
}

// Round 2
// 268.156 us; speedup vs baseline: 1.0087x; 1.0087x over previous
//
#include <hip/hip_runtime.h>
#include <hip/hip_bf16.h>
#include <stdint.h>

typedef __bf16 bf16;
typedef __attribute__((ext_vector_type(8))) __bf16 bf16x8;
typedef __attribute__((ext_vector_type(4))) float f32x4;

typedef __attribute__((address_space(3))) char* lds_ptr;
typedef const __attribute__((address_space(1))) char* glb_ptr;

#define BZ 4
#define NN 2048
#define CC 1024

__device__ __forceinline__ void gload_lds16(const bf16* g, bf16* l) {
    __builtin_amdgcn_global_load_lds((glb_ptr)g, (lds_ptr)l, 16, 0, 0);
}

// ---------------- fp32 -> bf16 flat convert (8 elems/thread) ----------------
__global__ void cvt_f32_bf16(const float* __restrict__ in, bf16* __restrict__ out, int n8) {
    int i = blockIdx.x * blockDim.x + threadIdx.x;
    if (i >= n8) return;
    const float4* p = (const float4*)in;
    float4 a = p[2 * i], b = p[2 * i + 1];
    bf16x8 o;
    o[0] = (bf16)a.x; o[1] = (bf16)a.y; o[2] = (bf16)a.z; o[3] = (bf16)a.w;
    o[4] = (bf16)b.x; o[5] = (bf16)b.y; o[6] = (bf16)b.z; o[7] = (bf16)b.w;
    *(bf16x8*)(out + 8 * (size_t)i) = o;
}

// ---------------- W [C][C] f32 -> Wt [C][C] bf16 transposed ----------------
__global__ void transposeW(const float* __restrict__ W, bf16* __restrict__ Wt) {
    __shared__ bf16 t[32][33];
    int d0 = blockIdx.x * 32, c0 = blockIdx.y * 32;
    int tx = threadIdx.x, ty = threadIdx.y;  // 32x8
#pragma unroll
    for (int i = 0; i < 4; i++)
        t[ty + 8 * i][tx] = (bf16)W[(size_t)(c0 + ty + 8 * i) * CC + d0 + tx];
    __syncthreads();
#pragma unroll
    for (int i = 0; i < 4; i++)
        Wt[(size_t)(d0 + ty + 8 * i) * CC + c0 + tx] = t[tx][ty + 8 * i];
}

// ---------------- v [B*N][C] bf16 -> vT [B][C][N] bf16 ----------------
__global__ void transposeV(const bf16* __restrict__ V, bf16* __restrict__ VT) {
    __shared__ bf16 t[32][33];
    int b = blockIdx.z;
    int n0 = blockIdx.x * 32, c0 = blockIdx.y * 32;
    const bf16* Vb = V + (size_t)b * NN * CC;
    bf16* Tb = VT + (size_t)b * CC * NN;
    int tx = threadIdx.x, ty = threadIdx.y;  // 32x8
#pragma unroll
    for (int i = 0; i < 4; i++)
        t[ty + 8 * i][tx] = Vb[(size_t)(n0 + ty + 8 * i) * CC + c0 + tx];
    __syncthreads();
#pragma unroll
    for (int i = 0; i < 4; i++)
        Tb[(size_t)(c0 + ty + 8 * i) * NN + n0 + tx] = t[tx][ty + 8 * i];
}

// ---------------- bf16 B^T GEMM (m97 structure): C = scale*A@Bt^T + bias ----
// Linear LDS [128][32] (64B rows), global_load_lds width=16 staging,
// single buffer, 2 barriers per K-step.
template <bool OUT_F32>
__global__ __launch_bounds__(256) void gemm_bt(
    const bf16* __restrict__ A, const bf16* __restrict__ Bt,
    void* __restrict__ Cout, const float* __restrict__ bias,
    int M, int Nd, int K, float scale,
    long long sA, long long sB, long long sC) {
    constexpr int BM = 128, BN = 128, BK = 32;
    __shared__ __align__(16) bf16 As[BM * BK];
    __shared__ __align__(16) bf16 Bs[BN * BK];
    const int b = blockIdx.z;
    A += (size_t)b * sA;
    Bt += (size_t)b * sB;
    const int m0 = blockIdx.y * BM, n0 = blockIdx.x * BN;
    const int t = threadIdx.x;
    const int wave = t >> 6, lane = t & 63;
    const int wm = (wave >> 1) * 64, wn = (wave & 1) * 64;  // 2x2 waves of 64x64
    f32x4 acc[4][4] = {};

    // staging geometry: per wave, rows [wave*32, wave*32+32), two 16-row calls.
    // lane l covers row wave*32 + c*16 + l/4, col chunk (l&3)*8 bf16 (16B),
    // matching HW's lds_base + lane*16 linear write.
    const int srow = wave * 32 + (lane >> 2);
    const int scol = (lane & 3) * 8;
    const int fr = lane & 15, hk = (lane >> 4) * 8;

    const bf16* gA = A + (size_t)(m0 + srow) * K + scol;
    const bf16* gB = Bt + (size_t)(n0 + srow) * K + scol;
    bf16* lA0 = &As[(wave * 32) * BK];
    bf16* lA1 = &As[(wave * 32 + 16) * BK];
    bf16* lB0 = &Bs[(wave * 32) * BK];
    bf16* lB1 = &Bs[(wave * 32 + 16) * BK];

    for (int k0 = 0; k0 < K; k0 += BK) {
        __syncthreads();  // prior iteration's ds_reads complete
        gload_lds16(gA + k0, lA0);
        gload_lds16(gA + k0 + (size_t)16 * K, lA1);
        gload_lds16(gB + k0, lB0);
        gload_lds16(gB + k0 + (size_t)16 * K, lB1);
        __syncthreads();  // compiler drains vmcnt(0) before barrier
        bf16x8 af[4], bfr[4];
#pragma unroll
        for (int i = 0; i < 4; i++)
            af[i] = *(const bf16x8*)&As[(wm + i * 16 + fr) * BK + hk];
#pragma unroll
        for (int j = 0; j < 4; j++)
            bfr[j] = *(const bf16x8*)&Bs[(wn + j * 16 + fr) * BK + hk];
#pragma unroll
        for (int i = 0; i < 4; i++)
#pragma unroll
            for (int j = 0; j < 4; j++)
                acc[i][j] = __builtin_amdgcn_mfma_f32_16x16x32_bf16(af[i], bfr[j], acc[i][j], 0, 0, 0);
    }

    const int rq = (lane >> 4) * 4;
#pragma unroll
    for (int i = 0; i < 4; i++) {
#pragma unroll
        for (int j = 0; j < 4; j++) {
            int col = n0 + wn + j * 16 + fr;
            float bb = bias ? bias[col] : 0.f;
#pragma unroll
            for (int r = 0; r < 4; r++) {
                int row = m0 + wm + i * 16 + rq + r;
                float v = acc[i][j][r] * scale + bb;
                if (OUT_F32)
                    ((float*)Cout)[(size_t)b * sC + (size_t)row * Nd + col] = v;
                else
                    ((bf16*)Cout)[(size_t)b * sC + (size_t)row * Nd + col] = (bf16)v;
            }
        }
    }
}

// ---------------- row softmax in place, rows of 2048 bf16 ----------------
__global__ __launch_bounds__(256) void softmax_rows(bf16* __restrict__ S) {
    const size_t row = blockIdx.x;
    bf16* p = S + row * (size_t)NN;
    const int t = threadIdx.x;
    bf16x8 vv = *(const bf16x8*)(p + t * 8);
    float f[8];
    float m = -1e30f;
#pragma unroll
    for (int i = 0; i < 8; i++) { f[i] = (float)vv[i]; m = fmaxf(m, f[i]); }
#pragma unroll
    for (int off = 32; off; off >>= 1) m = fmaxf(m, __shfl_xor(m, off));
    __shared__ float redm[4], reds[4];
    int wave = t >> 6, lane = t & 63;
    if (lane == 0) redm[wave] = m;
    __syncthreads();
    m = fmaxf(fmaxf(redm[0], redm[1]), fmaxf(redm[2], redm[3]));
    float s = 0.f;
#pragma unroll
    for (int i = 0; i < 8; i++) { f[i] = __expf(f[i] - m); s += f[i]; }
#pragma unroll
    for (int off = 32; off; off >>= 1) s += __shfl_xor(s, off);
    if (lane == 0) reds[wave] = s;
    __syncthreads();
    s = reds[0] + reds[1] + reds[2] + reds[3];
    float inv = 1.f / s;
    bf16x8 ov;
#pragma unroll
    for (int i = 0; i < 8; i++) ov[i] = (bf16)(f[i] * inv);
    *(bf16x8*)(p + t * 8) = ov;
}

extern "C" void kernel_launch(void* const* d_in, const int* in_sizes, int n_in,
                              void* d_out, int out_size, void* d_ws, size_t ws_size,
                              hipStream_t stream) {
    const float* event_f = (const float*)d_in[0];
    const float* img_f   = (const float*)d_in[1];
    const float* Wq = (const float*)d_in[2];
    const float* bq = (const float*)d_in[3];
    const float* Wk = (const float*)d_in[4];
    const float* bk = (const float*)d_in[5];
    const float* Wv = (const float*)d_in[6];
    const float* bv = (const float*)d_in[7];
    float* out = (float*)d_out;

    bf16* ws = (bf16*)d_ws;
    size_t off = 0;
    const size_t MC = (size_t)BZ * NN * CC;  // 8388608
    bf16* Ebf = ws + off; off += MC;
    bf16* Ibf = ws + off; off += MC;
    bf16* Wqt = ws + off; off += (size_t)CC * CC;
    bf16* Wkt = ws + off; off += (size_t)CC * CC;
    bf16* Wvt = ws + off; off += (size_t)CC * CC;
    bf16* Q   = ws + off; off += MC;
    bf16* K_  = ws + off; off += MC;
    bf16* V_  = ws + off; off += MC;
    bf16* VT  = ws + off; off += MC;
    bf16* S   = ws + off; off += (size_t)BZ * NN * NN;  // 16777216

    // 1. convert inputs to bf16
    {
        int n8 = (int)(MC / 8);
        cvt_f32_bf16<<<dim3((n8 + 255) / 256), dim3(256), 0, stream>>>(event_f, Ebf, n8);
        cvt_f32_bf16<<<dim3((n8 + 255) / 256), dim3(256), 0, stream>>>(img_f, Ibf, n8);
    }
    // 2. transpose weights to bf16 [d][c]
    {
        dim3 g(CC / 32, CC / 32), b(32, 8);
        transposeW<<<g, b, 0, stream>>>(Wq, Wqt);
        transposeW<<<g, b, 0, stream>>>(Wk, Wkt);
        transposeW<<<g, b, 0, stream>>>(Wv, Wvt);
    }
    // 3. projections: q/k/v = X @ W + b  (M=8192, N=1024, K=1024)
    {
        dim3 g(CC / 128, (BZ * NN) / 128, 1), b(256);
        gemm_bt<false><<<g, b, 0, stream>>>(Ebf, Wqt, Q,  bq, BZ * NN, CC, CC, 1.f, 0, 0, 0);
        gemm_bt<false><<<g, b, 0, stream>>>(Ibf, Wkt, K_, bk, BZ * NN, CC, CC, 1.f, 0, 0, 0);
        gemm_bt<false><<<g, b, 0, stream>>>(Ibf, Wvt, V_, bv, BZ * NN, CC, CC, 1.f, 0, 0, 0);
    }
    // 4. transpose V per batch -> [B][C][N]
    {
        dim3 g(NN / 32, CC / 32, BZ), b(32, 8);
        transposeV<<<g, b, 0, stream>>>(V_, VT);
    }
    // 5. S = Q @ K^T * (1/32)   (per batch: 2048x2048, K=1024)
    {
        dim3 g(NN / 128, NN / 128, BZ), b(256);
        gemm_bt<false><<<g, b, 0, stream>>>(Q, K_, S, nullptr, NN, NN, CC,
                                            1.f / 32.f,
                                            (long long)NN * CC, (long long)NN * CC,
                                            (long long)NN * NN);
    }
    // 6. softmax rows in place
    softmax_rows<<<dim3(BZ * NN), dim3(256), 0, stream>>>(S);
    // 7. out = P @ V  (per batch: 2048x1024, K=2048) -> fp32 d_out
    {
        dim3 g(CC / 128, NN / 128, BZ), b(256);
        gemm_bt<true><<<g, b, 0, stream>>>(S, VT, out, nullptr, NN, CC, NN, 1.f,
                                           (long long)NN * NN, (long long)CC * NN,
                                           (long long)NN * CC);
    }
}

// Round 3
// 226.389 us; speedup vs baseline: 1.1948x; 1.1845x over previous
//
#include <hip/hip_runtime.h>
#include <hip/hip_bf16.h>
#include <stdint.h>

typedef __bf16 bf16;
typedef __attribute__((ext_vector_type(8))) __bf16 bf16x8;
typedef __attribute__((ext_vector_type(4))) float f32x4;

typedef __attribute__((address_space(3))) char* lds_ptr;
typedef const __attribute__((address_space(1))) char* glb_ptr;

#define BZ 4
#define NN 2048
#define CC 1024

__device__ __forceinline__ void gload_lds16(const bf16* g, bf16* l) {
    __builtin_amdgcn_global_load_lds((glb_ptr)g, (lds_ptr)l, 16, 0, 0);
}

__device__ __forceinline__ void bar() {
    asm volatile("" ::: "memory");
    __builtin_amdgcn_s_barrier();
    asm volatile("" ::: "memory");
}

// ---------------- fp32 -> bf16 flat convert (8 elems/thread) ----------------
__global__ void cvt_f32_bf16(const float* __restrict__ in, bf16* __restrict__ out, int n8) {
    int i = blockIdx.x * blockDim.x + threadIdx.x;
    if (i >= n8) return;
    const float4* p = (const float4*)in;
    float4 a = p[2 * i], b = p[2 * i + 1];
    bf16x8 o;
    o[0] = (bf16)a.x; o[1] = (bf16)a.y; o[2] = (bf16)a.z; o[3] = (bf16)a.w;
    o[4] = (bf16)b.x; o[5] = (bf16)b.y; o[6] = (bf16)b.z; o[7] = (bf16)b.w;
    *(bf16x8*)(out + 8 * (size_t)i) = o;
}

// ------- W [C][C] f32 -> out [d][c] bf16 transposed (out base passed) -------
__global__ void transposeW(const float* __restrict__ W, bf16* __restrict__ Wt) {
    __shared__ bf16 t[32][33];
    int d0 = blockIdx.x * 32, c0 = blockIdx.y * 32;
    int tx = threadIdx.x, ty = threadIdx.y;  // 32x8
#pragma unroll
    for (int i = 0; i < 4; i++)
        t[ty + 8 * i][tx] = (bf16)W[(size_t)(c0 + ty + 8 * i) * CC + d0 + tx];
    __syncthreads();
#pragma unroll
    for (int i = 0; i < 4; i++)
        Wt[(size_t)(d0 + ty + 8 * i) * CC + c0 + tx] = t[tx][ty + 8 * i];
}

// ------- V (strided rows) -> VT [B][C][N] bf16 -------
__global__ void transposeV(const bf16* __restrict__ KVb, bf16* __restrict__ VT) {
    __shared__ bf16 t[32][33];
    int b = blockIdx.z;
    int n0 = blockIdx.x * 32, c0 = blockIdx.y * 32;
    const bf16* Vb = KVb + (size_t)b * NN * (2 * CC) + CC;  // V section, row stride 2C
    bf16* Tb = VT + (size_t)b * CC * NN;
    int tx = threadIdx.x, ty = threadIdx.y;  // 32x8
#pragma unroll
    for (int i = 0; i < 4; i++)
        t[ty + 8 * i][tx] = Vb[(size_t)(n0 + ty + 8 * i) * (2 * CC) + c0 + tx];
    __syncthreads();
#pragma unroll
    for (int i = 0; i < 4; i++)
        Tb[(size_t)(c0 + ty + 8 * i) * NN + n0 + tx] = t[tx][ty + 8 * i];
}

__global__ void concat_bias(const float* __restrict__ a, const float* __restrict__ b,
                            float* __restrict__ o) {
    int i = blockIdx.x * blockDim.x + threadIdx.x;  // 2048
    o[i] = (i < CC) ? a[i] : b[i - CC];
}

// ================= 256x256 8-phase bf16 B^T GEMM =================
// C[m][n] = scale * sum_k A[m][k]*Bt[n][k] + bias[n]
// 512 threads = 8 waves (2M x 4N), per-wave 128x64 output.
// BK=64, 2 LDS buffers (A[256][64]+B[256][64] each = 64KB), total 128KB.
// Staging: one 16KB half-tile per phase via global_load_lds w=16,
// pre-swizzled global source (chunk ^= row&7), swizzled ds_read.
// vmcnt(2) once per K-tile (phase P3) -- never drained to 0 in-loop.

#define STAGE_A(kt_, hh_)                                                        \
    do {                                                                         \
        int _kt = (kt_);                                                         \
        if (_kt < nkt) {                                                         \
            const bf16* _s = gAs + (size_t)((hh_)*128) * lda + (size_t)_kt * 64; \
            bf16* _d = &LA[_kt & 1][((hh_)*128 + wid * 16) * 64];                \
            gload_lds16(_s, _d);                                                 \
            gload_lds16(_s + (size_t)8 * lda, _d + 8 * 64);                      \
        }                                                                        \
    } while (0)

#define STAGE_B(kt_, hh_)                                                        \
    do {                                                                         \
        int _kt = (kt_);                                                         \
        if (_kt < nkt) {                                                         \
            const bf16* _s = gBs + (size_t)((hh_)*128) * ldb + (size_t)_kt * 64; \
            bf16* _d = &LB[_kt & 1][((hh_)*128 + wid * 16) * 64];                \
            gload_lds16(_s, _d);                                                 \
            gload_lds16(_s + (size_t)8 * ldb, _d + 8 * 64);                      \
        }                                                                        \
    } while (0)

#define LDA_FRAG(buf_, mh_)                                                      \
    do {                                                                         \
        _Pragma("unroll") for (int _i = 0; _i < 4; ++_i)                         \
            _Pragma("unroll") for (int _ks = 0; _ks < 2; ++_ks)                  \
                a[_i][_ks] = *(const bf16x8*)&LA[buf_][                          \
                    (wm + (mh_)*64 + _i * 16 + fr) * 64 +                        \
                    (((_ks * 4 + hi) ^ lo) * 8)];                                \
    } while (0)

#define LDB_FRAG(buf_, nh_, dst_)                                                \
    do {                                                                         \
        _Pragma("unroll") for (int _j = 0; _j < 2; ++_j)                         \
            _Pragma("unroll") for (int _ks = 0; _ks < 2; ++_ks)                  \
                dst_[_j][_ks] = *(const bf16x8*)&LB[buf_][                       \
                    (wn + (nh_)*32 + _j * 16 + fr) * 64 +                        \
                    (((_ks * 4 + hi) ^ lo) * 8)];                                \
    } while (0)

#define MMQ(mh_, nh_, b_)                                                        \
    do {                                                                         \
        __builtin_amdgcn_s_setprio(1);                                           \
        _Pragma("unroll") for (int _i = 0; _i < 4; ++_i)                         \
            _Pragma("unroll") for (int _j = 0; _j < 2; ++_j)                     \
                _Pragma("unroll") for (int _ks = 0; _ks < 2; ++_ks)              \
                    acc[(mh_)*4 + _i][(nh_)*2 + _j] =                            \
                        __builtin_amdgcn_mfma_f32_16x16x32_bf16(                 \
                            a[_i][_ks], b_[_j][_ks],                             \
                            acc[(mh_)*4 + _i][(nh_)*2 + _j], 0, 0, 0);           \
        __builtin_amdgcn_s_setprio(0);                                           \
    } while (0)

template <bool OUT_F32>
__global__ __launch_bounds__(512, 2) void gemm8(
    const bf16* __restrict__ A, int lda,
    const bf16* __restrict__ Bt, int ldb,
    void* __restrict__ Cout, int ldc,
    const float* __restrict__ bias, float scale,
    long long sA, long long sB, long long sC, int nkt) {
    __shared__ __align__(16) bf16 LA[2][256 * 64];
    __shared__ __align__(16) bf16 LB[2][256 * 64];
    const int bz = blockIdx.z;
    A += (size_t)bz * sA;
    Bt += (size_t)bz * sB;
    const int m0 = blockIdx.y * 256, n0 = blockIdx.x * 256;
    const int t = threadIdx.x, wid = t >> 6, lane = t & 63;
    const int wm = (wid >> 2) * 128, wn = (wid & 3) * 64;
    const int fr = lane & 15, hi = lane >> 4, lo = lane & 7;
    f32x4 acc[8][4] = {};

    // staging lane geometry: within a wave's 1KB DMA (8 rows x 128B),
    // lane covers row lane>>3, chunk lane&7; source chunk pre-swizzled.
    const int srow = lane >> 3;
    const int schunk = lo ^ srow;
    const bf16* gAs = A + (size_t)(m0 + wid * 16 + srow) * lda + schunk * 8;
    const bf16* gBs = Bt + (size_t)(n0 + wid * 16 + srow) * ldb + schunk * 8;

    // prologue: K-tile0 fully + K-tile1 A.h0; keep 2 loads in flight
    STAGE_A(0, 0); STAGE_A(0, 1); STAGE_B(0, 0); STAGE_B(0, 1); STAGE_A(1, 0);
    asm volatile("s_waitcnt vmcnt(2)" ::: "memory");
    bar();

    bf16x8 a[4][2], b0[2][2], b1[2][2];
    for (int kt = 0; kt < nkt; ++kt) {
        const int buf = kt & 1;
        // P0: read A-half0 + B-half0, stage next A.h1, mfma (A0,B0)
        LDA_FRAG(buf, 0);
        LDB_FRAG(buf, 0, b0);
        STAGE_A(kt + 1, 1);
        bar();
        MMQ(0, 0, b0);
        bar();
        // P1: read B-half1, stage next B.h0, mfma (A0,B1)
        LDB_FRAG(buf, 1, b1);
        STAGE_B(kt + 1, 0);
        bar();
        MMQ(0, 1, b1);
        bar();
        // P2: read A-half1, stage next B.h1, mfma (A1,B1)
        LDA_FRAG(buf, 1);
        STAGE_B(kt + 1, 1);
        bar();
        MMQ(1, 1, b1);
        bar();
        // P3: stage kt+2 A.h0, counted vmcnt -> K-tile kt+1 landed, mfma (A1,B0)
        STAGE_A(kt + 2, 0);
        asm volatile("s_waitcnt vmcnt(2)" ::: "memory");
        bar();
        MMQ(1, 0, b0);
        bar();
    }

    // epilogue: C write (C/D map: col=lane&15, row=(lane>>4)*4+reg)
    const int rq = hi * 4;
#pragma unroll
    for (int mh = 0; mh < 2; mh++)
#pragma unroll
        for (int i = 0; i < 4; i++)
#pragma unroll
            for (int nh = 0; nh < 2; nh++)
#pragma unroll
                for (int j = 0; j < 2; j++) {
                    int col = n0 + wn + nh * 32 + j * 16 + fr;
                    float bb = bias ? bias[col] : 0.f;
                    f32x4 v = acc[mh * 4 + i][nh * 2 + j];
                    int row = m0 + wm + mh * 64 + i * 16 + rq;
#pragma unroll
                    for (int r = 0; r < 4; r++) {
                        float o = v[r] * scale + bb;
                        if (OUT_F32)
                            ((float*)Cout)[(size_t)bz * sC + (size_t)(row + r) * ldc + col] = o;
                        else
                            ((bf16*)Cout)[(size_t)bz * sC + (size_t)(row + r) * ldc + col] = (bf16)o;
                    }
                }
}

// ---------------- row softmax in place, rows of 2048 bf16 ----------------
__global__ __launch_bounds__(256) void softmax_rows(bf16* __restrict__ S) {
    const size_t row = blockIdx.x;
    bf16* p = S + row * (size_t)NN;
    const int t = threadIdx.x;
    bf16x8 vv = *(const bf16x8*)(p + t * 8);
    float f[8];
    float m = -1e30f;
#pragma unroll
    for (int i = 0; i < 8; i++) { f[i] = (float)vv[i]; m = fmaxf(m, f[i]); }
#pragma unroll
    for (int off = 32; off; off >>= 1) m = fmaxf(m, __shfl_xor(m, off));
    __shared__ float redm[4], reds[4];
    int wave = t >> 6, lane = t & 63;
    if (lane == 0) redm[wave] = m;
    __syncthreads();
    m = fmaxf(fmaxf(redm[0], redm[1]), fmaxf(redm[2], redm[3]));
    float s = 0.f;
#pragma unroll
    for (int i = 0; i < 8; i++) { f[i] = __expf(f[i] - m); s += f[i]; }
#pragma unroll
    for (int off = 32; off; off >>= 1) s += __shfl_xor(s, off);
    if (lane == 0) reds[wave] = s;
    __syncthreads();
    s = reds[0] + reds[1] + reds[2] + reds[3];
    float inv = 1.f / s;
    bf16x8 ov;
#pragma unroll
    for (int i = 0; i < 8; i++) ov[i] = (bf16)(f[i] * inv);
    *(bf16x8*)(p + t * 8) = ov;
}

extern "C" void kernel_launch(void* const* d_in, const int* in_sizes, int n_in,
                              void* d_out, int out_size, void* d_ws, size_t ws_size,
                              hipStream_t stream) {
    const float* event_f = (const float*)d_in[0];
    const float* img_f   = (const float*)d_in[1];
    const float* Wq = (const float*)d_in[2];
    const float* bq = (const float*)d_in[3];
    const float* Wk = (const float*)d_in[4];
    const float* bk = (const float*)d_in[5];
    const float* Wv = (const float*)d_in[6];
    const float* bv = (const float*)d_in[7];
    float* out = (float*)d_out;

    bf16* ws = (bf16*)d_ws;
    const size_t MC = (size_t)BZ * NN * CC;  // 8388608
    // layout (bf16 elements); S aliases Ebf+Ibf (dead after projections)
    bf16* Ebf  = ws;                       // MC
    bf16* Ibf  = ws + MC;                  // MC
    bf16* S    = ws;                       // 2*MC (reuses Ebf+Ibf)
    size_t off = 2 * MC;
    bf16* Wqt  = ws + off; off += (size_t)CC * CC;        // 1M
    bf16* Wkvt = ws + off; off += (size_t)2 * CC * CC;    // 2M
    bf16* Qb   = ws + off; off += MC;                     // [8192][1024]
    bf16* KVb  = ws + off; off += 2 * MC;                 // [8192][2048]
    bf16* VT   = ws + off; off += MC;                     // [B][1024][2048]
    float* bkv = (float*)(ws + off);                      // 2048 f32

    // 1. convert inputs to bf16
    {
        int n8 = (int)(MC / 8);
        cvt_f32_bf16<<<dim3((n8 + 255) / 256), dim3(256), 0, stream>>>(event_f, Ebf, n8);
        cvt_f32_bf16<<<dim3((n8 + 255) / 256), dim3(256), 0, stream>>>(img_f, Ibf, n8);
    }
    // 2. transpose weights; Wk,Wv concatenated row-wise into Wkvt [2048][1024]
    {
        dim3 g(CC / 32, CC / 32), b(32, 8);
        transposeW<<<g, b, 0, stream>>>(Wq, Wqt);
        transposeW<<<g, b, 0, stream>>>(Wk, Wkvt);
        transposeW<<<g, b, 0, stream>>>(Wv, Wkvt + (size_t)CC * CC);
        concat_bias<<<dim3(8), dim3(256), 0, stream>>>(bk, bv, bkv);
    }
    // 3a. q = event @ Wq + bq  (M=8192, N=1024, K=1024)
    gemm8<false><<<dim3(CC / 256, (BZ * NN) / 256, 1), dim3(512), 0, stream>>>(
        Ebf, CC, Wqt, CC, Qb, CC, bq, 1.f, 0, 0, 0, CC / 64);
    // 3b. [k|v] = img @ [Wk|Wv] + [bk|bv]  (M=8192, N=2048, K=1024)
    gemm8<false><<<dim3((2 * CC) / 256, (BZ * NN) / 256, 1), dim3(512), 0, stream>>>(
        Ibf, CC, Wkvt, CC, KVb, 2 * CC, bkv, 1.f, 0, 0, 0, CC / 64);
    // 4. transpose V per batch -> [B][C][N]
    {
        dim3 g(NN / 32, CC / 32, BZ), b(32, 8);
        transposeV<<<g, b, 0, stream>>>(KVb, VT);
    }
    // 5. S = Q @ K^T * (1/32)  (per batch 2048x2048, K=1024)
    gemm8<false><<<dim3(NN / 256, NN / 256, BZ), dim3(512), 0, stream>>>(
        Qb, CC, KVb, 2 * CC, S, NN, nullptr, 1.f / 32.f,
        (long long)NN * CC, (long long)NN * 2 * CC, (long long)NN * NN, CC / 64);
    // 6. softmax rows in place
    softmax_rows<<<dim3(BZ * NN), dim3(256), 0, stream>>>(S);
    // 7. out = P @ V  (per batch 2048x1024, K=2048) -> fp32
    gemm8<true><<<dim3(CC / 256, NN / 256, BZ), dim3(512), 0, stream>>>(
        S, NN, VT, NN, out, CC, nullptr, 1.f,
        (long long)NN * NN, (long long)CC * NN, (long long)NN * CC, NN / 64);
}